// Round 3
// baseline (270.365 us; speedup 1.0000x reference)
//
#include <hip/hip_runtime.h>
#include <hip/hip_bf16.h>
#include <math.h>

// SAM2 MultiScale Block — round 10: mlp operand-swapped GEMMs.
//  - GEMM1/GEMM2 pass weights as the A-operand, activations as B (fragment
//    lane maps are identical, so packings/reads unchanged). D is transposed:
//    lane = token, regs = 4 contiguous channel-quads.
//  - GEMM1 epilogue: 16x ds_write_b16 -> 4x ds_write_b64 (v_cvt_pk_bf16_f32).
//  - GEMM2 epilogue: 16x scalar ld/st -> 4x float4 residual ld + 4x float4 st.
// attn/aproj/respool/ln1/cast identical to R9.
// DIM=112(K pad 128), DIM_OUT=224, HEADS=4, HD=56, WS=8, QS=2, MLP=896
//
// ws layout (bytes):
//   hs_bf @ 0          : 131072x112 bf16 = 29,360,128
//   hs2   @ 29,360,128 : 32768x224 f32   = 29,360,128
//   o_bf  @ 58,720,256 : 32768x224 bf16  = 14,680,064
//   wF    @ 73,400,320 : frag-packed bf16 weights (elems):
//     qkvF 704x128 @ +0       rpF 224x128 @ +90112   apF 224x224 @ +118784
//     m1F  896x224 @ +168960  m2F 224x896 @ +369664  (end 570368)
// 16x16 frag order (qkvF/rpF/apF): (n,k) -> tile=(n/16)*KT+(k/32);
//   flat=(tile*64+lane)*8+j, lane=((k%32)/8)*16+(n%16), j=k%8.
// 32x32 frag order (m1F/m2F): (n,k) -> tile=(n/32)*KT16+(k/16);
//   flat=(tile*64+lane)*8+j, lane=((k%16)/8)*32+(n%32), j=k%8.

#define SCALE_A 0.13363062095621219f  // 56^-0.5

typedef __attribute__((ext_vector_type(8))) short short8;
typedef __attribute__((ext_vector_type(4))) short short4v;
typedef __attribute__((ext_vector_type(4))) float f32x4;
typedef __attribute__((ext_vector_type(16))) float f32x16;
typedef __attribute__((ext_vector_type(2))) unsigned uint2v;

__device__ inline short f2bf(float x) {
  union { float f; unsigned u; } v; v.f = x;
  unsigned r = v.u + 0x7fff + ((v.u >> 16) & 1);
  return (short)(r >> 16);
}
// packed f32x2 -> bf16x2 (RNE), single instruction on gfx950
__device__ inline unsigned pk2bf(float a, float b) {
  unsigned r;
  asm("v_cvt_pk_bf16_f32 %0, %1, %2" : "=v"(r) : "v"(a), "v"(b));
  return r;
}
// sigmoid-form tanh-GELU: x * sigmoid(1.59576912*(x + 0.044715 x^3)).
__device__ inline float gelu_fast(float x) {
  float x2 = x * x;
  float p = fmaf(x2, 0.044715f, 1.0f);
  float t = -1.5957691216057308f * x * p;
  return x / (1.0f + __expf(t));
}

// ------------------------------------------- weight cast to frag order
__global__ void cast_w_kernel(const float* __restrict__ qkv_w,
                              const float* __restrict__ rp_w,
                              const float* __restrict__ ap_w,
                              const float* __restrict__ m1_w,
                              const float* __restrict__ m2_w,
                              short* __restrict__ wF) {
  int tid = blockIdx.x * blockDim.x + threadIdx.x;
  int stride = gridDim.x * blockDim.x;
  // qkvF: permuted cols cp = h*176 + cl; cl: [q 0..55|k 56..111|v 112..167|pad]
  for (int e = tid; e < 90112; e += stride) {
    int j = e & 7, lr = (e >> 3) & 15, lqq = (e >> 7) & 3, tile = e >> 9;
    int kt = tile & 3, nt = tile >> 2;
    int cp = nt * 16 + lr;
    int h = cp / 176, cl = cp % 176;
    int k = kt * 32 + lqq * 8 + j;
    float val = 0.f;
    if (k < 112 && cl < 168) {
      int bcol = (cl < 56) ? (h * 56 + cl)
               : (cl < 112) ? (224 + h * 56 + (cl - 56))
                            : (448 + h * 56 + (cl - 112));
      val = qkv_w[k * 672 + bcol];
    }
    wF[e] = f2bf(val);
  }
  for (int e = tid; e < 28672; e += stride) {  // rpF: N=224, KT=4 (16x16)
    int j = e & 7, lr = (e >> 3) & 15, lqq = (e >> 7) & 3, tile = e >> 9;
    int kt = tile & 3, nt = tile >> 2;
    int n = nt * 16 + lr, k = kt * 32 + lqq * 8 + j;
    wF[90112 + e] = (k < 112) ? f2bf(rp_w[k * 224 + n]) : (short)0;
  }
  for (int e = tid; e < 50176; e += stride) {  // apF: N=224, KT=7 (16x16)
    int j = e & 7, lr = (e >> 3) & 15, lqq = (e >> 7) & 3, tile = e >> 9;
    int kt = tile % 7, nt = tile / 7;
    int n = nt * 16 + lr, k = kt * 32 + lqq * 8 + j;
    wF[118784 + e] = f2bf(ap_w[k * 224 + n]);
  }
  for (int e = tid; e < 200704; e += stride) {  // m1F: N=896/32, K=224/16 (32x32)
    int j = e & 7, lane = (e >> 3) & 63, unit = e >> 9;
    int kt = unit % 14, nt = unit / 14;
    int n = nt * 32 + (lane & 31), k = kt * 16 + (lane >> 5) * 8 + j;
    wF[168960 + e] = f2bf(m1_w[k * 896 + n]);
  }
  for (int e = tid; e < 200704; e += stride) {  // m2F: N=224/32, K=896/16 (32x32)
    int j = e & 7, lane = (e >> 3) & 63, unit = e >> 9;
    int kt = unit % 56, nt = unit / 56;
    int n = nt * 32 + (lane & 31), k = kt * 16 + (lane >> 5) * 8 + j;
    wF[369664 + e] = f2bf(m2_w[k * 224 + n]);
  }
}

// ---------------------------------------------------------------- LN1 -> bf16
__global__ __launch_bounds__(256) void ln1_kernel(
    const float* __restrict__ x, const float* __restrict__ g,
    const float* __restrict__ b, short* __restrict__ hs) {
  int row = blockIdx.x * 4 + (threadIdx.x >> 6);
  int lane = threadIdx.x & 63;
  const float* rp = x + (size_t)row * 112;
  float v0 = rp[lane];
  float v1 = (lane < 48) ? rp[64 + lane] : 0.f;
  float s = v0 + v1;
  #pragma unroll
  for (int off = 32; off; off >>= 1) s += __shfl_down(s, off);
  s = __shfl(s, 0);
  float mean = s * (1.f / 112.f);
  float d0 = v0 - mean;
  float d1 = (lane < 48) ? (v1 - mean) : 0.f;
  float s2 = d0 * d0 + d1 * d1;
  #pragma unroll
  for (int off = 32; off; off >>= 1) s2 += __shfl_down(s2, off);
  s2 = __shfl(s2, 0);
  float rs = rsqrtf(s2 * (1.f / 112.f) + 1e-6f);
  short* op = hs + (size_t)row * 112;
  op[lane] = f2bf(d0 * rs * g[lane] + b[lane]);
  if (lane < 48) op[64 + lane] = f2bf(d1 * rs * g[64 + lane] + b[64 + lane]);
}

// -------------------------------------- res_proj + maxpool2 (MFMA) -> hs2
__global__ __launch_bounds__(256, 8) void respool_kernel(
    const short* __restrict__ hs, const short* __restrict__ rpF,
    const float* __restrict__ bias, float* __restrict__ hs2) {
  __shared__ alignas(16) short w_s[64 * 136];
  int blk = blockIdx.x;  // 2048
  int tid = threadIdx.x;
  for (int e = tid; e < 1024; e += 256) {
    int m = e >> 4, c = e & 15;
    short8* dst = (short8*)&w_s[m * 136 + c * 8];
    if (c < 14) {
      int p = m >> 2, r = m & 3;
      int pix = blk * 16 + p;
      int bb = pix >> 12, ii = (pix >> 6) & 63, jj = pix & 63;
      size_t token = ((size_t)(bb * 128 + 2 * ii + (r >> 1))) * 128 + 2 * jj + (r & 1);
      *dst = *(const short8*)(hs + token * 112 + c * 8);
    } else {
      short8 z = {0, 0, 0, 0, 0, 0, 0, 0};
      *dst = z;
    }
  }
  __syncthreads();
  int wave = tid >> 6, lane = tid & 63, lrow = lane & 15, lq = lane >> 4;
  short8 Ar[4];
  #pragma unroll
  for (int kt = 0; kt < 4; ++kt)
    Ar[kt] = *(const short8*)&w_s[(wave * 16 + lrow) * 136 + kt * 32 + lq * 8];
  int p = wave * 4 + lq;
  for (int pr = 0; pr < 7; ++pr) {
    int c0 = pr * 32 + lrow, c1 = c0 + 16;
    f32x4 acc0 = {0.f, 0.f, 0.f, 0.f}, acc1 = {0.f, 0.f, 0.f, 0.f};
    #pragma unroll
    for (int kt = 0; kt < 4; ++kt) {
      short8 b0 = *(const short8*)(rpF + (((2 * pr) * 4 + kt) * 64 + lane) * 8);
      short8 b1 = *(const short8*)(rpF + (((2 * pr + 1) * 4 + kt) * 64 + lane) * 8);
      acc0 = __builtin_amdgcn_mfma_f32_16x16x32_bf16(Ar[kt], b0, acc0, 0, 0, 0);
      acc1 = __builtin_amdgcn_mfma_f32_16x16x32_bf16(Ar[kt], b1, acc1, 0, 0, 0);
    }
    float m0 = fmaxf(fmaxf(acc0[0], acc0[1]), fmaxf(acc0[2], acc0[3])) + bias[c0];
    float m1 = fmaxf(fmaxf(acc1[0], acc1[1]), fmaxf(acc1[2], acc1[3])) + bias[c1];
    hs2[(size_t)(blk * 16 + p) * 224 + c0] = m0;
    hs2[(size_t)(blk * 16 + p) * 224 + c1] = m1;
  }
}

// ------------------- fused windowed attention, round 9: head-per-wave
__global__ __launch_bounds__(256, 2) void attn_kernel(
    const short* __restrict__ hs, const short* __restrict__ qkvF,
    const float* __restrict__ qkv_b, short* __restrict__ o_bf) {
  __shared__ alignas(16) short u_s[4 * 9792];   // 78,336 B
  int win = blockIdx.x;                         // 2048
  int nw = win & 15, nh = (win >> 4) & 15, b = win >> 8;
  int tid = threadIdx.x;
  int wave = tid >> 6, lane = tid & 63, lrow = lane & 15, lq = lane >> 4;
  short* w_s  = u_s;                    // [64*136] staging (union, hoist only)
  short* k_s  = u_s + wave * 9792;      // private
  short* vT_s = k_s + 4608;
  short* qp_s = k_s + 8640;

  for (int e = tid; e < 1024; e += 256) {
    int m = e >> 4, c = e & 15;
    short8* dst = (short8*)&w_s[m * 136 + c * 8];
    if (c < 14) {
      int p = m >> 2, r = m & 3;
      int tr = (p >> 2) * 2 + (r >> 1), tc = (p & 3) * 2 + (r & 1);
      size_t token = ((size_t)(b * 128 + nh * 8 + tr)) * 128 + (nw * 8 + tc);
      *dst = *(const short8*)(hs + token * 112 + c * 8);
    } else {
      short8 z = {0, 0, 0, 0, 0, 0, 0, 0};
      *dst = z;
    }
  }
  __syncthreads();  // staging done

  // hoist A-frags for all 4 M-tiles: 64 VGPR
  short8 Aw[4][4];
  #pragma unroll
  for (int mt = 0; mt < 4; ++mt)
    #pragma unroll
    for (int kt = 0; kt < 4; ++kt)
      Aw[mt][kt] = *(const short8*)&w_s[(mt * 16 + lrow) * 136 + kt * 32 + lq * 8];
  __syncthreads();  // hoists done; per-wave regions may be written

  // zero pads (per-wave, one short8 store per lane)
  {
    short8 z = {0, 0, 0, 0, 0, 0, 0, 0};
    *(short8*)&k_s[lane * 72 + 56] = z;          // k pad cols 56..63, 64 rows
    if (lane < 16) *(short8*)&qp_s[lane * 72 + 56] = z;  // q pad
  }

  int h = wave;  // head ownership

  // ---- qkv: 11 N-tiles for this head, all 4 M-tiles
  #pragma unroll 2
  for (int t = 0; t < 11; ++t) {
    int cl = t * 16 + lrow;
    f32x4 ac[4] = {{0.f,0.f,0.f,0.f},{0.f,0.f,0.f,0.f},
                   {0.f,0.f,0.f,0.f},{0.f,0.f,0.f,0.f}};
    short8 bw[4];
    #pragma unroll
    for (int kt = 0; kt < 4; ++kt)
      bw[kt] = *(const short8*)(qkvF + (((h * 11 + t) * 4 + kt) * 64 + lane) * 8);
    #pragma unroll
    for (int kt = 0; kt < 4; ++kt)
      #pragma unroll
      for (int mt = 0; mt < 4; ++mt)
        ac[mt] = __builtin_amdgcn_mfma_f32_16x16x32_bf16(Aw[mt][kt], bw[kt], ac[mt], 0, 0, 0);
    if (cl < 56) {
      float bias = qkv_b[h * 56 + cl];
      #pragma unroll
      for (int mt = 0; mt < 4; ++mt) {
        float mx = fmaxf(fmaxf(ac[mt][0], ac[mt][1]),
                         fmaxf(ac[mt][2], ac[mt][3])) + bias;
        qp_s[(mt * 4 + lq) * 72 + cl] = f2bf(mx * SCALE_A);
      }
    } else if (cl < 112) {
      float bias = qkv_b[224 + h * 56 + (cl - 56)];
      #pragma unroll
      for (int mt = 0; mt < 4; ++mt)
        #pragma unroll
        for (int r = 0; r < 4; ++r)
          k_s[(mt * 16 + lq * 4 + r) * 72 + (cl - 56)] = f2bf(ac[mt][r] + bias);
    } else if (cl < 168) {
      float bias = qkv_b[448 + h * 56 + (cl - 112)];
      #pragma unroll
      for (int mt = 0; mt < 4; ++mt) {
        short4v pk = {f2bf(ac[mt][0] + bias), f2bf(ac[mt][1] + bias),
                      f2bf(ac[mt][2] + bias), f2bf(ac[mt][3] + bias)};
        *(short4v*)&vT_s[(cl - 112) * 72 + mt * 16 + lq * 4] = pk;
      }
    }
  }
  // no barrier: same-wave LDS write->read (waitcnt handles it)

  // ---- scores: 16 queries x 64 keys
  short8 aq[2];
  #pragma unroll
  for (int kt = 0; kt < 2; ++kt)
    aq[kt] = *(const short8*)&qp_s[lrow * 72 + kt * 32 + lq * 8];
  f32x4 sc[4];
  #pragma unroll
  for (int t = 0; t < 4; ++t) {
    sc[t][0] = sc[t][1] = sc[t][2] = sc[t][3] = 0.f;
    #pragma unroll
    for (int kt = 0; kt < 2; ++kt) {
      short8 bk = *(const short8*)&k_s[(t * 16 + lrow) * 72 + kt * 32 + lq * 8];
      sc[t] = __builtin_amdgcn_mfma_f32_16x16x32_bf16(aq[kt], bk, sc[t], 0, 0, 0);
    }
  }
  // ---- softmax rows lq*4+r: reduce over t (local) and lrow (16-lane shfl)
  float mr[4], sr[4];
  #pragma unroll
  for (int r = 0; r < 4; ++r)
    mr[r] = fmaxf(fmaxf(sc[0][r], sc[1][r]), fmaxf(sc[2][r], sc[3][r]));
  #pragma unroll
  for (int off = 8; off; off >>= 1)
    #pragma unroll
    for (int r = 0; r < 4; ++r) mr[r] = fmaxf(mr[r], __shfl_xor(mr[r], off, 16));
  #pragma unroll
  for (int r = 0; r < 4; ++r) {
    #pragma unroll
    for (int t = 0; t < 4; ++t) sc[t][r] = __expf(sc[t][r] - mr[r]);
    sr[r] = sc[0][r] + sc[1][r] + sc[2][r] + sc[3][r];
  }
  #pragma unroll
  for (int off = 8; off; off >>= 1)
    #pragma unroll
    for (int r = 0; r < 4; ++r) sr[r] += __shfl_xor(sr[r], off, 16);
  #pragma unroll
  for (int r = 0; r < 4; ++r) sr[r] = 1.f / sr[r];
  // normalized P -> qp_s (q is dead; same-wave write->read, no barrier)
  #pragma unroll
  for (int t = 0; t < 4; ++t)
    #pragma unroll
    for (int r = 0; r < 4; ++r)
      qp_s[(lq * 4 + r) * 72 + t * 16 + lrow] = f2bf(sc[t][r] * sr[r]);

  // ---- PV: all 56 cols; tiles {0,16,32,40}, 4th overlaps (store lrow>=8)
  short8 ap[2];
  #pragma unroll
  for (int kt = 0; kt < 2; ++kt)
    ap[kt] = *(const short8*)&qp_s[lrow * 72 + kt * 32 + lq * 8];
  #pragma unroll
  for (int ct = 0; ct < 4; ++ct) {
    int c0 = (ct < 3) ? ct * 16 : 40;
    int col = c0 + lrow;
    f32x4 ov = {0.f, 0.f, 0.f, 0.f};
    #pragma unroll
    for (int kt = 0; kt < 2; ++kt) {
      short8 bv = *(const short8*)&vT_s[col * 72 + kt * 32 + lq * 8];
      ov = __builtin_amdgcn_mfma_f32_16x16x32_bf16(ap[kt], bv, ov, 0, 0, 0);
    }
    if (ct < 3 || lrow >= 8) {
      #pragma unroll
      for (int r = 0; r < 4; ++r) {
        int row = lq * 4 + r;
        size_t token = ((size_t)(b * 64 + nh * 4 + (row >> 2))) * 64 + (nw * 4 + (row & 3));
        o_bf[token * 224 + h * 56 + col] = f2bf(ov[r]);
      }
    }
  }
}

// ---------------------------- attn_proj GEMM + bias + residual into hs2
__global__ __launch_bounds__(256, 5) void aproj_kernel(
    const short* __restrict__ o_bf, const short* __restrict__ apF,
    const float* __restrict__ apb, float* __restrict__ hs2) {
  __shared__ alignas(16) short o_s[64 * 232];
  int blk = blockIdx.x;  // 512 x 64 tokens
  int tid = threadIdx.x;
  for (int e = tid; e < 64 * 28; e += 256) {
    int m = e / 28, c = e % 28;
    *(short8*)&o_s[m * 232 + c * 8] =
        *(const short8*)(o_bf + ((size_t)blk * 64 + m) * 224 + c * 8);
  }
  __syncthreads();
  int wave = tid >> 6, lane = tid & 63, lrow = lane & 15, lq = lane >> 4;
  short8 Ao[7];
  #pragma unroll
  for (int kt = 0; kt < 7; ++kt)
    Ao[kt] = *(const short8*)&o_s[(wave * 16 + lrow) * 232 + kt * 32 + lq * 8];
  for (int pr = 0; pr < 7; ++pr) {
    int c0 = pr * 32 + lrow, c1 = c0 + 16;
    f32x4 acc0 = {0.f, 0.f, 0.f, 0.f}, acc1 = {0.f, 0.f, 0.f, 0.f};
    #pragma unroll
    for (int kt = 0; kt < 7; ++kt) {
      short8 b0 = *(const short8*)(apF + (((2 * pr) * 7 + kt) * 64 + lane) * 8);
      short8 b1 = *(const short8*)(apF + (((2 * pr + 1) * 7 + kt) * 64 + lane) * 8);
      acc0 = __builtin_amdgcn_mfma_f32_16x16x32_bf16(Ao[kt], b0, acc0, 0, 0, 0);
      acc1 = __builtin_amdgcn_mfma_f32_16x16x32_bf16(Ao[kt], b1, acc1, 0, 0, 0);
    }
    float bi0 = apb[c0], bi1 = apb[c1];
    #pragma unroll
    for (int r = 0; r < 4; ++r) {
      size_t row = (size_t)blk * 64 + wave * 16 + lq * 4 + r;
      hs2[row * 224 + c0] += acc0[r] + bi0;
      hs2[row * 224 + c1] += acc1[r] + bi1;
    }
  }
}

// ------------- fused LN2 + mlp1 + GELU + mlp2 + residual, 32x32x16 MFMA
// R10: operand-swapped (weights=A, activations=B). D: lane=token, regs=4
// contiguous channel-quads -> vectorized epilogues.
template <int NT>
__device__ __forceinline__ void mlp1_tiles(
    int nt0, const short* ln_s, const short* __restrict__ m1F,
    const float* __restrict__ b1, short* hid_s, int nl, int half, int lane) {
  f32x16 acc[NT];
  #pragma unroll
  for (int i = 0; i < NT; ++i)
    #pragma unroll
    for (int r = 0; r < 16; ++r) acc[i][r] = 0.f;
  #pragma unroll
  for (int kt = 0; kt < 14; ++kt) {
    short8 a = *(const short8*)&ln_s[nl * 232 + kt * 16 + half * 8];
    #pragma unroll
    for (int i = 0; i < NT; ++i) {
      short8 bw = *(const short8*)(m1F + ((size_t)((nt0 + i) * 14 + kt) * 64 + lane) * 8);
      acc[i] = __builtin_amdgcn_mfma_f32_32x32x16_bf16(bw, a, acc[i], 0, 0, 0);
    }
  }
  #pragma unroll
  for (int i = 0; i < NT; ++i) {
    int ch_base = (nt0 + i) * 32;
    #pragma unroll
    for (int rq = 0; rq < 4; ++rq) {
      int ch0 = ch_base + 8 * rq + 4 * half;
      f32x4 bq = *(const f32x4*)&b1[ch0];
      float g0 = gelu_fast(acc[i][4 * rq + 0] + bq[0]);
      float g1 = gelu_fast(acc[i][4 * rq + 1] + bq[1]);
      float g2 = gelu_fast(acc[i][4 * rq + 2] + bq[2]);
      float g3 = gelu_fast(acc[i][4 * rq + 3] + bq[3]);
      uint2v w = {pk2bf(g0, g1), pk2bf(g2, g3)};
      *(uint2v*)&hid_s[nl * 904 + ch0] = w;
    }
  }
}

__global__ __launch_bounds__(512, 4) void mlp_kernel(
    const float* __restrict__ hs2, const float* __restrict__ g2,
    const float* __restrict__ b2, const short* __restrict__ m1F,
    const float* __restrict__ b1, const short* __restrict__ m2F,
    const float* __restrict__ b2b, float* __restrict__ out) {
  __shared__ alignas(16) short ln_s[32 * 232];   // 14,848 B
  __shared__ alignas(16) short hid_s[32 * 904];  // 57,856 B => 72,704 B
  int blk = blockIdx.x;  // 1024 x 32 tokens
  int tid = threadIdx.x;
  size_t base = (size_t)blk * 32 * 224;
  {
    int row = tid >> 4, l = tid & 15;
    const float* rp = hs2 + base + (size_t)row * 224;
    float v[14];
    float s = 0.f;
    #pragma unroll
    for (int c = 0; c < 14; ++c) { v[c] = rp[l + 16 * c]; s += v[c]; }
    #pragma unroll
    for (int off = 8; off; off >>= 1) s += __shfl_xor(s, off, 16);
    float mean = s * (1.f / 224.f);
    float s2 = 0.f;
    #pragma unroll
    for (int c = 0; c < 14; ++c) { float d = v[c] - mean; s2 = fmaf(d, d, s2); }
    #pragma unroll
    for (int off = 8; off; off >>= 1) s2 += __shfl_xor(s2, off, 16);
    float rs = rsqrtf(s2 * (1.f / 224.f) + 1e-6f);
    #pragma unroll
    for (int c = 0; c < 14; ++c) {
      int cc = l + 16 * c;
      ln_s[row * 232 + cc] = f2bf((v[c] - mean) * rs * g2[cc] + b2[cc]);
    }
  }
  __syncthreads();
  int wave = tid >> 6, lane = tid & 63;
  int nl = lane & 31, half = lane >> 5;
  if (wave < 4) mlp1_tiles<4>(wave * 4, ln_s, m1F, b1, hid_s, nl, half, lane);
  else          mlp1_tiles<3>(16 + (wave - 4) * 3, ln_s, m1F, b1, hid_s, nl, half, lane);
  __syncthreads();
  if (wave < 7) {
    int nt = wave;
    int ch_base = nt * 32;
    // prefetch residual (token = nl): 4x float4, hides under the 56-MFMA k-loop
    f32x4 res[4];
    #pragma unroll
    for (int rq = 0; rq < 4; ++rq)
      res[rq] = *(const f32x4*)&hs2[base + (size_t)nl * 224 + ch_base + 8 * rq + 4 * half];
    f32x16 ac0 = {0.f,0.f,0.f,0.f,0.f,0.f,0.f,0.f,0.f,0.f,0.f,0.f,0.f,0.f,0.f,0.f};
    f32x16 ac1 = {0.f,0.f,0.f,0.f,0.f,0.f,0.f,0.f,0.f,0.f,0.f,0.f,0.f,0.f,0.f,0.f};
    #pragma unroll 4
    for (int kt = 0; kt < 56; kt += 2) {
      short8 a0 = *(const short8*)&hid_s[nl * 904 + kt * 16 + half * 8];
      short8 a1 = *(const short8*)&hid_s[nl * 904 + (kt + 1) * 16 + half * 8];
      short8 b0 = *(const short8*)(m2F + ((size_t)(nt * 56 + kt) * 64 + lane) * 8);
      short8 b1 = *(const short8*)(m2F + ((size_t)(nt * 56 + kt + 1) * 64 + lane) * 8);
      ac0 = __builtin_amdgcn_mfma_f32_32x32x16_bf16(b0, a0, ac0, 0, 0, 0);
      ac1 = __builtin_amdgcn_mfma_f32_32x32x16_bf16(b1, a1, ac1, 0, 0, 0);
    }
    #pragma unroll
    for (int rq = 0; rq < 4; ++rq) {
      int ch0 = ch_base + 8 * rq + 4 * half;
      f32x4 bq = *(const f32x4*)&b2b[ch0];
      f32x4 o;
      #pragma unroll
      for (int q = 0; q < 4; ++q)
        o[q] = res[rq][q] + ac0[4 * rq + q] + ac1[4 * rq + q] + bq[q];
      *(f32x4*)&out[base + (size_t)nl * 224 + ch0] = o;
    }
  }
}

extern "C" void kernel_launch(void* const* d_in, const int* in_sizes, int n_in,
                              void* d_out, int out_size, void* d_ws, size_t ws_size,
                              hipStream_t stream) {
  const float* x    = (const float*)d_in[0];
  const float* ln1g = (const float*)d_in[1];
  const float* ln1b = (const float*)d_in[2];
  const float* qkvw = (const float*)d_in[3];
  const float* qkvb = (const float*)d_in[4];
  const float* apw  = (const float*)d_in[5];
  const float* apb  = (const float*)d_in[6];
  const float* rpw  = (const float*)d_in[7];
  const float* rpb  = (const float*)d_in[8];
  const float* ln2g = (const float*)d_in[9];
  const float* ln2b = (const float*)d_in[10];
  const float* w1   = (const float*)d_in[11];
  const float* b1   = (const float*)d_in[12];
  const float* w2   = (const float*)d_in[13];
  const float* b2   = (const float*)d_in[14];
  float* out = (float*)d_out;

  short* hs_bf = (short*)d_ws;
  float* hs2   = (float*)((char*)d_ws + 29360128);
  short* o_bf  = (short*)((char*)d_ws + 58720256);
  short* wF    = (short*)((char*)d_ws + 73400320);

  cast_w_kernel<<<1024, 256, 0, stream>>>(qkvw, rpw, apw, w1, w2, wF);
  ln1_kernel<<<32768, 256, 0, stream>>>(x, ln1g, ln1b, hs_bf);
  respool_kernel<<<2048, 256, 0, stream>>>(hs_bf, wF + 90112, rpb, hs2);
  attn_kernel<<<2048, 256, 0, stream>>>(hs_bf, wF, qkvb, o_bf);
  aproj_kernel<<<512, 256, 0, stream>>>(o_bf, wF + 118784, apb, hs2);
  mlp_kernel<<<1024, 512, 0, stream>>>(hs2, ln2g, ln2b, wF + 168960, b1,
                                       wF + 369664, b2, out);
}

// Round 4
// 256.431 us; speedup vs baseline: 1.0543x; 1.0543x over previous
//
#include <hip/hip_runtime.h>
#include <hip/hip_bf16.h>
#include <math.h>

// SAM2 MultiScale Block — round 11:
//  - REVERT mlp to R9 (lane=channel epilogues). R10's operand swap caused
//    8-way LDS bank conflicts on hid_s writes + uncoalesced global I/O
//    (lane=token => 896B lane stride) + inline-asm cvt_pk scheduling loss.
//  - ln1 rewrite: f32x4 loads (16B/lane, was 4B scalar), 2 rows/wave,
//    shfl_xor(32) reduce, short4 packed bf16 stores. 16384 blocks.
// attn/aproj/respool/cast identical to R9/R10.
// DIM=112(K pad 128), DIM_OUT=224, HEADS=4, HD=56, WS=8, QS=2, MLP=896
//
// ws layout (bytes):
//   hs_bf @ 0          : 131072x112 bf16 = 29,360,128
//   hs2   @ 29,360,128 : 32768x224 f32   = 29,360,128
//   o_bf  @ 58,720,256 : 32768x224 bf16  = 14,680,064
//   wF    @ 73,400,320 : frag-packed bf16 weights (elems):
//     qkvF 704x128 @ +0       rpF 224x128 @ +90112   apF 224x224 @ +118784
//     m1F  896x224 @ +168960  m2F 224x896 @ +369664  (end 570368)
// 16x16 frag order (qkvF/rpF/apF): (n,k) -> tile=(n/16)*KT+(k/32);
//   flat=(tile*64+lane)*8+j, lane=((k%32)/8)*16+(n%16), j=k%8.
// 32x32 frag order (m1F/m2F): (n,k) -> tile=(n/32)*KT16+(k/16);
//   flat=(tile*64+lane)*8+j, lane=((k%16)/8)*32+(n%32), j=k%8.

#define SCALE_A 0.13363062095621219f  // 56^-0.5

typedef __attribute__((ext_vector_type(8))) short short8;
typedef __attribute__((ext_vector_type(4))) short short4v;
typedef __attribute__((ext_vector_type(4))) float f32x4;
typedef __attribute__((ext_vector_type(16))) float f32x16;

__device__ inline short f2bf(float x) {
  union { float f; unsigned u; } v; v.f = x;
  unsigned r = v.u + 0x7fff + ((v.u >> 16) & 1);
  return (short)(r >> 16);
}
// sigmoid-form tanh-GELU: x * sigmoid(1.59576912*(x + 0.044715 x^3)).
__device__ inline float gelu_fast(float x) {
  float x2 = x * x;
  float p = fmaf(x2, 0.044715f, 1.0f);
  float t = -1.5957691216057308f * x * p;
  return x / (1.0f + __expf(t));
}

// ------------------------------------------- weight cast to frag order
__global__ void cast_w_kernel(const float* __restrict__ qkv_w,
                              const float* __restrict__ rp_w,
                              const float* __restrict__ ap_w,
                              const float* __restrict__ m1_w,
                              const float* __restrict__ m2_w,
                              short* __restrict__ wF) {
  int tid = blockIdx.x * blockDim.x + threadIdx.x;
  int stride = gridDim.x * blockDim.x;
  // qkvF: permuted cols cp = h*176 + cl; cl: [q 0..55|k 56..111|v 112..167|pad]
  for (int e = tid; e < 90112; e += stride) {
    int j = e & 7, lr = (e >> 3) & 15, lqq = (e >> 7) & 3, tile = e >> 9;
    int kt = tile & 3, nt = tile >> 2;
    int cp = nt * 16 + lr;
    int h = cp / 176, cl = cp % 176;
    int k = kt * 32 + lqq * 8 + j;
    float val = 0.f;
    if (k < 112 && cl < 168) {
      int bcol = (cl < 56) ? (h * 56 + cl)
               : (cl < 112) ? (224 + h * 56 + (cl - 56))
                            : (448 + h * 56 + (cl - 112));
      val = qkv_w[k * 672 + bcol];
    }
    wF[e] = f2bf(val);
  }
  for (int e = tid; e < 28672; e += stride) {  // rpF: N=224, KT=4 (16x16)
    int j = e & 7, lr = (e >> 3) & 15, lqq = (e >> 7) & 3, tile = e >> 9;
    int kt = tile & 3, nt = tile >> 2;
    int n = nt * 16 + lr, k = kt * 32 + lqq * 8 + j;
    wF[90112 + e] = (k < 112) ? f2bf(rp_w[k * 224 + n]) : (short)0;
  }
  for (int e = tid; e < 50176; e += stride) {  // apF: N=224, KT=7 (16x16)
    int j = e & 7, lr = (e >> 3) & 15, lqq = (e >> 7) & 3, tile = e >> 9;
    int kt = tile % 7, nt = tile / 7;
    int n = nt * 16 + lr, k = kt * 32 + lqq * 8 + j;
    wF[118784 + e] = f2bf(ap_w[k * 224 + n]);
  }
  for (int e = tid; e < 200704; e += stride) {  // m1F: N=896/32, K=224/16 (32x32)
    int j = e & 7, lane = (e >> 3) & 63, unit = e >> 9;
    int kt = unit % 14, nt = unit / 14;
    int n = nt * 32 + (lane & 31), k = kt * 16 + (lane >> 5) * 8 + j;
    wF[168960 + e] = f2bf(m1_w[k * 896 + n]);
  }
  for (int e = tid; e < 200704; e += stride) {  // m2F: N=224/32, K=896/16 (32x32)
    int j = e & 7, lane = (e >> 3) & 63, unit = e >> 9;
    int kt = unit % 56, nt = unit / 56;
    int n = nt * 32 + (lane & 31), k = kt * 16 + (lane >> 5) * 8 + j;
    wF[369664 + e] = f2bf(m2_w[k * 224 + n]);
  }
}

// ---------------------------------------------------------------- LN1 -> bf16
// R11: 2 rows/wave, f32x4 loads (lanes 0..27 of each 32-half), shfl_xor(32)
// reduce, short4 bf16 stores. 8 rows/block, 16384 blocks.
__global__ __launch_bounds__(256) void ln1_kernel(
    const float* __restrict__ x, const float* __restrict__ g,
    const float* __restrict__ b, short* __restrict__ hs) {
  int wave = threadIdx.x >> 6, lane = threadIdx.x & 63;
  int half = lane >> 5, sub = lane & 31;
  size_t row = (size_t)blockIdx.x * 8 + wave * 2 + half;
  const float* rp = x + row * 112;
  f32x4 v = {0.f, 0.f, 0.f, 0.f};
  if (sub < 28) v = *(const f32x4*)(rp + sub * 4);
  float s = v[0] + v[1] + v[2] + v[3];
  #pragma unroll
  for (int off = 16; off; off >>= 1) s += __shfl_xor(s, off, 32);
  float mean = s * (1.f / 112.f);
  float s2 = 0.f;
  #pragma unroll
  for (int q = 0; q < 4; ++q) { float d = v[q] - mean; s2 = fmaf(d, d, s2); }
  if (sub >= 28) s2 = 0.f;
  #pragma unroll
  for (int off = 16; off; off >>= 1) s2 += __shfl_xor(s2, off, 32);
  float rs = rsqrtf(s2 * (1.f / 112.f) + 1e-6f);
  if (sub < 28) {
    f32x4 gg = *(const f32x4*)(g + sub * 4);
    f32x4 bb = *(const f32x4*)(b + sub * 4);
    short4v o;
    #pragma unroll
    for (int q = 0; q < 4; ++q)
      o[q] = f2bf((v[q] - mean) * rs * gg[q] + bb[q]);
    *(short4v*)(hs + row * 112 + sub * 4) = o;
  }
}

// -------------------------------------- res_proj + maxpool2 (MFMA) -> hs2
__global__ __launch_bounds__(256, 8) void respool_kernel(
    const short* __restrict__ hs, const short* __restrict__ rpF,
    const float* __restrict__ bias, float* __restrict__ hs2) {
  __shared__ alignas(16) short w_s[64 * 136];
  int blk = blockIdx.x;  // 2048
  int tid = threadIdx.x;
  for (int e = tid; e < 1024; e += 256) {
    int m = e >> 4, c = e & 15;
    short8* dst = (short8*)&w_s[m * 136 + c * 8];
    if (c < 14) {
      int p = m >> 2, r = m & 3;
      int pix = blk * 16 + p;
      int bb = pix >> 12, ii = (pix >> 6) & 63, jj = pix & 63;
      size_t token = ((size_t)(bb * 128 + 2 * ii + (r >> 1))) * 128 + 2 * jj + (r & 1);
      *dst = *(const short8*)(hs + token * 112 + c * 8);
    } else {
      short8 z = {0, 0, 0, 0, 0, 0, 0, 0};
      *dst = z;
    }
  }
  __syncthreads();
  int wave = tid >> 6, lane = tid & 63, lrow = lane & 15, lq = lane >> 4;
  short8 Ar[4];
  #pragma unroll
  for (int kt = 0; kt < 4; ++kt)
    Ar[kt] = *(const short8*)&w_s[(wave * 16 + lrow) * 136 + kt * 32 + lq * 8];
  int p = wave * 4 + lq;
  for (int pr = 0; pr < 7; ++pr) {
    int c0 = pr * 32 + lrow, c1 = c0 + 16;
    f32x4 acc0 = {0.f, 0.f, 0.f, 0.f}, acc1 = {0.f, 0.f, 0.f, 0.f};
    #pragma unroll
    for (int kt = 0; kt < 4; ++kt) {
      short8 b0 = *(const short8*)(rpF + (((2 * pr) * 4 + kt) * 64 + lane) * 8);
      short8 b1 = *(const short8*)(rpF + (((2 * pr + 1) * 4 + kt) * 64 + lane) * 8);
      acc0 = __builtin_amdgcn_mfma_f32_16x16x32_bf16(Ar[kt], b0, acc0, 0, 0, 0);
      acc1 = __builtin_amdgcn_mfma_f32_16x16x32_bf16(Ar[kt], b1, acc1, 0, 0, 0);
    }
    float m0 = fmaxf(fmaxf(acc0[0], acc0[1]), fmaxf(acc0[2], acc0[3])) + bias[c0];
    float m1 = fmaxf(fmaxf(acc1[0], acc1[1]), fmaxf(acc1[2], acc1[3])) + bias[c1];
    hs2[(size_t)(blk * 16 + p) * 224 + c0] = m0;
    hs2[(size_t)(blk * 16 + p) * 224 + c1] = m1;
  }
}

// ------------------- fused windowed attention, round 9: head-per-wave
__global__ __launch_bounds__(256, 2) void attn_kernel(
    const short* __restrict__ hs, const short* __restrict__ qkvF,
    const float* __restrict__ qkv_b, short* __restrict__ o_bf) {
  __shared__ alignas(16) short u_s[4 * 9792];   // 78,336 B
  int win = blockIdx.x;                         // 2048
  int nw = win & 15, nh = (win >> 4) & 15, b = win >> 8;
  int tid = threadIdx.x;
  int wave = tid >> 6, lane = tid & 63, lrow = lane & 15, lq = lane >> 4;
  short* w_s  = u_s;                    // [64*136] staging (union, hoist only)
  short* k_s  = u_s + wave * 9792;      // private
  short* vT_s = k_s + 4608;
  short* qp_s = k_s + 8640;

  for (int e = tid; e < 1024; e += 256) {
    int m = e >> 4, c = e & 15;
    short8* dst = (short8*)&w_s[m * 136 + c * 8];
    if (c < 14) {
      int p = m >> 2, r = m & 3;
      int tr = (p >> 2) * 2 + (r >> 1), tc = (p & 3) * 2 + (r & 1);
      size_t token = ((size_t)(b * 128 + nh * 8 + tr)) * 128 + (nw * 8 + tc);
      *dst = *(const short8*)(hs + token * 112 + c * 8);
    } else {
      short8 z = {0, 0, 0, 0, 0, 0, 0, 0};
      *dst = z;
    }
  }
  __syncthreads();  // staging done

  // hoist A-frags for all 4 M-tiles: 64 VGPR
  short8 Aw[4][4];
  #pragma unroll
  for (int mt = 0; mt < 4; ++mt)
    #pragma unroll
    for (int kt = 0; kt < 4; ++kt)
      Aw[mt][kt] = *(const short8*)&w_s[(mt * 16 + lrow) * 136 + kt * 32 + lq * 8];
  __syncthreads();  // hoists done; per-wave regions may be written

  // zero pads (per-wave, one short8 store per lane)
  {
    short8 z = {0, 0, 0, 0, 0, 0, 0, 0};
    *(short8*)&k_s[lane * 72 + 56] = z;          // k pad cols 56..63, 64 rows
    if (lane < 16) *(short8*)&qp_s[lane * 72 + 56] = z;  // q pad
  }

  int h = wave;  // head ownership

  // ---- qkv: 11 N-tiles for this head, all 4 M-tiles
  #pragma unroll 2
  for (int t = 0; t < 11; ++t) {
    int cl = t * 16 + lrow;
    f32x4 ac[4] = {{0.f,0.f,0.f,0.f},{0.f,0.f,0.f,0.f},
                   {0.f,0.f,0.f,0.f},{0.f,0.f,0.f,0.f}};
    short8 bw[4];
    #pragma unroll
    for (int kt = 0; kt < 4; ++kt)
      bw[kt] = *(const short8*)(qkvF + (((h * 11 + t) * 4 + kt) * 64 + lane) * 8);
    #pragma unroll
    for (int kt = 0; kt < 4; ++kt)
      #pragma unroll
      for (int mt = 0; mt < 4; ++mt)
        ac[mt] = __builtin_amdgcn_mfma_f32_16x16x32_bf16(Aw[mt][kt], bw[kt], ac[mt], 0, 0, 0);
    if (cl < 56) {
      float bias = qkv_b[h * 56 + cl];
      #pragma unroll
      for (int mt = 0; mt < 4; ++mt) {
        float mx = fmaxf(fmaxf(ac[mt][0], ac[mt][1]),
                         fmaxf(ac[mt][2], ac[mt][3])) + bias;
        qp_s[(mt * 4 + lq) * 72 + cl] = f2bf(mx * SCALE_A);
      }
    } else if (cl < 112) {
      float bias = qkv_b[224 + h * 56 + (cl - 56)];
      #pragma unroll
      for (int mt = 0; mt < 4; ++mt)
        #pragma unroll
        for (int r = 0; r < 4; ++r)
          k_s[(mt * 16 + lq * 4 + r) * 72 + (cl - 56)] = f2bf(ac[mt][r] + bias);
    } else if (cl < 168) {
      float bias = qkv_b[448 + h * 56 + (cl - 112)];
      #pragma unroll
      for (int mt = 0; mt < 4; ++mt) {
        short4v pk = {f2bf(ac[mt][0] + bias), f2bf(ac[mt][1] + bias),
                      f2bf(ac[mt][2] + bias), f2bf(ac[mt][3] + bias)};
        *(short4v*)&vT_s[(cl - 112) * 72 + mt * 16 + lq * 4] = pk;
      }
    }
  }
  // no barrier: same-wave LDS write->read (waitcnt handles it)

  // ---- scores: 16 queries x 64 keys
  short8 aq[2];
  #pragma unroll
  for (int kt = 0; kt < 2; ++kt)
    aq[kt] = *(const short8*)&qp_s[lrow * 72 + kt * 32 + lq * 8];
  f32x4 sc[4];
  #pragma unroll
  for (int t = 0; t < 4; ++t) {
    sc[t][0] = sc[t][1] = sc[t][2] = sc[t][3] = 0.f;
    #pragma unroll
    for (int kt = 0; kt < 2; ++kt) {
      short8 bk = *(const short8*)&k_s[(t * 16 + lrow) * 72 + kt * 32 + lq * 8];
      sc[t] = __builtin_amdgcn_mfma_f32_16x16x32_bf16(aq[kt], bk, sc[t], 0, 0, 0);
    }
  }
  // ---- softmax rows lq*4+r: reduce over t (local) and lrow (16-lane shfl)
  float mr[4], sr[4];
  #pragma unroll
  for (int r = 0; r < 4; ++r)
    mr[r] = fmaxf(fmaxf(sc[0][r], sc[1][r]), fmaxf(sc[2][r], sc[3][r]));
  #pragma unroll
  for (int off = 8; off; off >>= 1)
    #pragma unroll
    for (int r = 0; r < 4; ++r) mr[r] = fmaxf(mr[r], __shfl_xor(mr[r], off, 16));
  #pragma unroll
  for (int r = 0; r < 4; ++r) {
    #pragma unroll
    for (int t = 0; t < 4; ++t) sc[t][r] = __expf(sc[t][r] - mr[r]);
    sr[r] = sc[0][r] + sc[1][r] + sc[2][r] + sc[3][r];
  }
  #pragma unroll
  for (int off = 8; off; off >>= 1)
    #pragma unroll
    for (int r = 0; r < 4; ++r) sr[r] += __shfl_xor(sr[r], off, 16);
  #pragma unroll
  for (int r = 0; r < 4; ++r) sr[r] = 1.f / sr[r];
  // normalized P -> qp_s (q is dead; same-wave write->read, no barrier)
  #pragma unroll
  for (int t = 0; t < 4; ++t)
    #pragma unroll
    for (int r = 0; r < 4; ++r)
      qp_s[(lq * 4 + r) * 72 + t * 16 + lrow] = f2bf(sc[t][r] * sr[r]);

  // ---- PV: all 56 cols; tiles {0,16,32,40}, 4th overlaps (store lrow>=8)
  short8 ap[2];
  #pragma unroll
  for (int kt = 0; kt < 2; ++kt)
    ap[kt] = *(const short8*)&qp_s[lrow * 72 + kt * 32 + lq * 8];
  #pragma unroll
  for (int ct = 0; ct < 4; ++ct) {
    int c0 = (ct < 3) ? ct * 16 : 40;
    int col = c0 + lrow;
    f32x4 ov = {0.f, 0.f, 0.f, 0.f};
    #pragma unroll
    for (int kt = 0; kt < 2; ++kt) {
      short8 bv = *(const short8*)&vT_s[col * 72 + kt * 32 + lq * 8];
      ov = __builtin_amdgcn_mfma_f32_16x16x32_bf16(ap[kt], bv, ov, 0, 0, 0);
    }
    if (ct < 3 || lrow >= 8) {
      #pragma unroll
      for (int r = 0; r < 4; ++r) {
        int row = lq * 4 + r;
        size_t token = ((size_t)(b * 64 + nh * 4 + (row >> 2))) * 64 + (nw * 4 + (row & 3));
        o_bf[token * 224 + h * 56 + col] = f2bf(ov[r]);
      }
    }
  }
}

// ---------------------------- attn_proj GEMM + bias + residual into hs2
__global__ __launch_bounds__(256, 5) void aproj_kernel(
    const short* __restrict__ o_bf, const short* __restrict__ apF,
    const float* __restrict__ apb, float* __restrict__ hs2) {
  __shared__ alignas(16) short o_s[64 * 232];
  int blk = blockIdx.x;  // 512 x 64 tokens
  int tid = threadIdx.x;
  for (int e = tid; e < 64 * 28; e += 256) {
    int m = e / 28, c = e % 28;
    *(short8*)&o_s[m * 232 + c * 8] =
        *(const short8*)(o_bf + ((size_t)blk * 64 + m) * 224 + c * 8);
  }
  __syncthreads();
  int wave = tid >> 6, lane = tid & 63, lrow = lane & 15, lq = lane >> 4;
  short8 Ao[7];
  #pragma unroll
  for (int kt = 0; kt < 7; ++kt)
    Ao[kt] = *(const short8*)&o_s[(wave * 16 + lrow) * 232 + kt * 32 + lq * 8];
  for (int pr = 0; pr < 7; ++pr) {
    int c0 = pr * 32 + lrow, c1 = c0 + 16;
    f32x4 acc0 = {0.f, 0.f, 0.f, 0.f}, acc1 = {0.f, 0.f, 0.f, 0.f};
    #pragma unroll
    for (int kt = 0; kt < 7; ++kt) {
      short8 b0 = *(const short8*)(apF + (((2 * pr) * 7 + kt) * 64 + lane) * 8);
      short8 b1 = *(const short8*)(apF + (((2 * pr + 1) * 7 + kt) * 64 + lane) * 8);
      acc0 = __builtin_amdgcn_mfma_f32_16x16x32_bf16(Ao[kt], b0, acc0, 0, 0, 0);
      acc1 = __builtin_amdgcn_mfma_f32_16x16x32_bf16(Ao[kt], b1, acc1, 0, 0, 0);
    }
    float bi0 = apb[c0], bi1 = apb[c1];
    #pragma unroll
    for (int r = 0; r < 4; ++r) {
      size_t row = (size_t)blk * 64 + wave * 16 + lq * 4 + r;
      hs2[row * 224 + c0] += acc0[r] + bi0;
      hs2[row * 224 + c1] += acc1[r] + bi1;
    }
  }
}

// ------------- fused LN2 + mlp1 + GELU + mlp2 + residual, 32x32x16 MFMA
// (R9 version: lane=channel epilogues, fused multi-tile GEMM1, res prefetch)
template <int NT>
__device__ __forceinline__ void mlp1_tiles(
    int nt0, const short* ln_s, const short* __restrict__ m1F,
    const float* __restrict__ b1, short* hid_s, int nl, int half, int lane) {
  f32x16 acc[NT];
  #pragma unroll
  for (int i = 0; i < NT; ++i)
    #pragma unroll
    for (int r = 0; r < 16; ++r) acc[i][r] = 0.f;
  #pragma unroll
  for (int kt = 0; kt < 14; ++kt) {
    short8 a = *(const short8*)&ln_s[nl * 232 + kt * 16 + half * 8];
    #pragma unroll
    for (int i = 0; i < NT; ++i) {
      short8 bw = *(const short8*)(m1F + ((size_t)((nt0 + i) * 14 + kt) * 64 + lane) * 8);
      acc[i] = __builtin_amdgcn_mfma_f32_32x32x16_bf16(a, bw, acc[i], 0, 0, 0);
    }
  }
  #pragma unroll
  for (int i = 0; i < NT; ++i) {
    int col = (nt0 + i) * 32 + nl;
    float bi = b1[col];
    #pragma unroll
    for (int r = 0; r < 16; ++r) {
      int row = (r & 3) + 8 * (r >> 2) + 4 * half;
      hid_s[row * 904 + col] = f2bf(gelu_fast(acc[i][r] + bi));
    }
  }
}

__global__ __launch_bounds__(512, 4) void mlp_kernel(
    const float* __restrict__ hs2, const float* __restrict__ g2,
    const float* __restrict__ b2, const short* __restrict__ m1F,
    const float* __restrict__ b1, const short* __restrict__ m2F,
    const float* __restrict__ b2b, float* __restrict__ out) {
  __shared__ alignas(16) short ln_s[32 * 232];   // 14,848 B
  __shared__ alignas(16) short hid_s[32 * 904];  // 57,856 B => 72,704 B
  int blk = blockIdx.x;  // 1024 x 32 tokens
  int tid = threadIdx.x;
  size_t base = (size_t)blk * 32 * 224;
  {
    int row = tid >> 4, l = tid & 15;
    const float* rp = hs2 + base + (size_t)row * 224;
    float v[14];
    float s = 0.f;
    #pragma unroll
    for (int c = 0; c < 14; ++c) { v[c] = rp[l + 16 * c]; s += v[c]; }
    #pragma unroll
    for (int off = 8; off; off >>= 1) s += __shfl_xor(s, off, 16);
    float mean = s * (1.f / 224.f);
    float s2 = 0.f;
    #pragma unroll
    for (int c = 0; c < 14; ++c) { float d = v[c] - mean; s2 = fmaf(d, d, s2); }
    #pragma unroll
    for (int off = 8; off; off >>= 1) s2 += __shfl_xor(s2, off, 16);
    float rs = rsqrtf(s2 * (1.f / 224.f) + 1e-6f);
    #pragma unroll
    for (int c = 0; c < 14; ++c) {
      int cc = l + 16 * c;
      ln_s[row * 232 + cc] = f2bf((v[c] - mean) * rs * g2[cc] + b2[cc]);
    }
  }
  __syncthreads();
  int wave = tid >> 6, lane = tid & 63;
  int nl = lane & 31, half = lane >> 5;
  if (wave < 4) mlp1_tiles<4>(wave * 4, ln_s, m1F, b1, hid_s, nl, half, lane);
  else          mlp1_tiles<3>(16 + (wave - 4) * 3, ln_s, m1F, b1, hid_s, nl, half, lane);
  __syncthreads();
  if (wave < 7) {
    int nt = wave;
    int col = nt * 32 + nl;
    float res[16];
    #pragma unroll
    for (int r = 0; r < 16; ++r) {
      int row = (r & 3) + 8 * (r >> 2) + 4 * half;
      res[r] = hs2[base + (size_t)row * 224 + col];
    }
    f32x16 ac0 = {0.f,0.f,0.f,0.f,0.f,0.f,0.f,0.f,0.f,0.f,0.f,0.f,0.f,0.f,0.f,0.f};
    f32x16 ac1 = {0.f,0.f,0.f,0.f,0.f,0.f,0.f,0.f,0.f,0.f,0.f,0.f,0.f,0.f,0.f,0.f};
    #pragma unroll 4
    for (int kt = 0; kt < 56; kt += 2) {
      short8 a0 = *(const short8*)&hid_s[nl * 904 + kt * 16 + half * 8];
      short8 a1 = *(const short8*)&hid_s[nl * 904 + (kt + 1) * 16 + half * 8];
      short8 b0 = *(const short8*)(m2F + ((size_t)(nt * 56 + kt) * 64 + lane) * 8);
      short8 b1 = *(const short8*)(m2F + ((size_t)(nt * 56 + kt + 1) * 64 + lane) * 8);
      ac0 = __builtin_amdgcn_mfma_f32_32x32x16_bf16(a0, b0, ac0, 0, 0, 0);
      ac1 = __builtin_amdgcn_mfma_f32_32x32x16_bf16(a1, b1, ac1, 0, 0, 0);
    }
    float bi = b2b[col];
    #pragma unroll
    for (int r = 0; r < 16; ++r) {
      int row = (r & 3) + 8 * (r >> 2) + 4 * half;
      size_t idx = base + (size_t)row * 224 + col;
      out[idx] = res[r] + ac0[r] + ac1[r] + bi;
    }
  }
}

extern "C" void kernel_launch(void* const* d_in, const int* in_sizes, int n_in,
                              void* d_out, int out_size, void* d_ws, size_t ws_size,
                              hipStream_t stream) {
  const float* x    = (const float*)d_in[0];
  const float* ln1g = (const float*)d_in[1];
  const float* ln1b = (const float*)d_in[2];
  const float* qkvw = (const float*)d_in[3];
  const float* qkvb = (const float*)d_in[4];
  const float* apw  = (const float*)d_in[5];
  const float* apb  = (const float*)d_in[6];
  const float* rpw  = (const float*)d_in[7];
  const float* rpb  = (const float*)d_in[8];
  const float* ln2g = (const float*)d_in[9];
  const float* ln2b = (const float*)d_in[10];
  const float* w1   = (const float*)d_in[11];
  const float* b1   = (const float*)d_in[12];
  const float* w2   = (const float*)d_in[13];
  const float* b2   = (const float*)d_in[14];
  float* out = (float*)d_out;

  short* hs_bf = (short*)d_ws;
  float* hs2   = (float*)((char*)d_ws + 29360128);
  short* o_bf  = (short*)((char*)d_ws + 58720256);
  short* wF    = (short*)((char*)d_ws + 73400320);

  cast_w_kernel<<<1024, 256, 0, stream>>>(qkvw, rpw, apw, w1, w2, wF);
  ln1_kernel<<<16384, 256, 0, stream>>>(x, ln1g, ln1b, hs_bf);
  respool_kernel<<<2048, 256, 0, stream>>>(hs_bf, wF + 90112, rpb, hs2);
  attn_kernel<<<2048, 256, 0, stream>>>(hs_bf, wF, qkvb, o_bf);
  aproj_kernel<<<512, 256, 0, stream>>>(o_bf, wF + 118784, apb, hs2);
  mlp_kernel<<<1024, 512, 0, stream>>>(hs2, ln2g, ln2b, wF + 168960, b1,
                                       wF + 369664, b2, out);
}